// Round 4
// baseline (536.061 us; speedup 1.0000x reference)
//
#include <hip/hip_runtime.h>

// Mixture-of-Experts, sparse top-2.
// Round 4: 256xBNt double-buffered 2-phase grouped GEMM, expert->XCD pinning,
// XOR-swizzled LDS staged via global_load_lds(16B).

#define E_N 8
#define TOPK 2
#define DM 1024
#define FF 4096
#define NTOK 4096
#define NA 8192
#define LN_EPS 1e-5f

typedef __attribute__((ext_vector_type(4))) float f32x4;
typedef __attribute__((ext_vector_type(8))) short short8;

__device__ __forceinline__ unsigned short f2bf(float f) {
    unsigned int u = __builtin_bit_cast(unsigned int, f);
    u = (u + 0x7FFFu + ((u >> 16) & 1u)) >> 16;   // RNE
    return (unsigned short)u;
}
__device__ __forceinline__ float bf2f(unsigned short h) {
    unsigned int u = ((unsigned int)h) << 16;
    return __builtin_bit_cast(float, u);
}
__device__ __forceinline__ void unp(unsigned int u, float& lo, float& hi) {
    lo = bf2f((unsigned short)(u & 0xffffu));
    hi = bf2f((unsigned short)(u >> 16));
}
__device__ __forceinline__ unsigned int pk(float lo, float hi) {
    return (unsigned int)f2bf(lo) | ((unsigned int)f2bf(hi) << 16);
}

__device__ __forceinline__ void gload16(const unsigned short* g, unsigned short* lds) {
    __builtin_amdgcn_global_load_lds(
        (const __attribute__((address_space(1))) unsigned int*)g,
        (__attribute__((address_space(3))) unsigned int*)lds, 16, 0, 0);
}

// ---------------- small utility kernels ----------------

__global__ void k_zero(int* p) { p[threadIdx.x] = 0; }

__global__ void k_conv_bf16(const float* __restrict__ src, unsigned short* __restrict__ dst, int n4) {
    int i = blockIdx.x * blockDim.x + threadIdx.x;
    if (i >= n4) return;
    float4 v = ((const float4*)src)[i];
    unsigned long long r =
        (unsigned long long)pk(v.x, v.y) | ((unsigned long long)pk(v.z, v.w) << 32);
    ((unsigned long long*)dst)[i] = r;
}

// [E][R][C] f32 -> [E][C][R] bf16, 64x64 tile. Conflict-free LDS, 16B stores.
__global__ __launch_bounds__(256) void k_transpose_bf16(const float* __restrict__ src,
        unsigned short* __restrict__ dst, int R, int C) {
    __shared__ float tile[64][65];
    size_t e = blockIdx.z;
    const float* s = src + e * (size_t)R * C + (size_t)(blockIdx.y * 64) * C + blockIdx.x * 64;
    unsigned short* d = dst + e * (size_t)R * C + (size_t)(blockIdx.x * 64) * R + blockIdx.y * 64;
    int tid = threadIdx.x;
    int lr = tid >> 4, lc = (tid & 15) * 4;
#pragma unroll
    for (int p = 0; p < 4; p++) {
        float4 v = *(const float4*)(s + (size_t)(lr + p * 16) * C + lc);
        tile[lr + p * 16][lc] = v.x;     tile[lr + p * 16][lc + 1] = v.y;
        tile[lr + p * 16][lc + 2] = v.z; tile[lr + p * 16][lc + 3] = v.w;
    }
    __syncthreads();
    int rc = (tid & 7) * 8;
#pragma unroll
    for (int p = 0; p < 2; p++) {
        int cc = (tid >> 3) + p * 32;
        float a0 = tile[rc + 0][cc], a1 = tile[rc + 1][cc];
        float a2 = tile[rc + 2][cc], a3 = tile[rc + 3][cc];
        float a4 = tile[rc + 4][cc], a5 = tile[rc + 5][cc];
        float a6 = tile[rc + 6][cc], a7 = tile[rc + 7][cc];
        uint4 o;
        o.x = pk(a0, a1); o.y = pk(a2, a3); o.z = pk(a4, a5); o.w = pk(a6, a7);
        *(uint4*)(d + (size_t)cc * R + rc) = o;
    }
}

// ---------------- router ----------------

__global__ __launch_bounds__(256) void k_router(const float* __restrict__ x,
        const float* __restrict__ Wr, const float* __restrict__ br,
        int* __restrict__ topk_idx, float* __restrict__ topk_p, int* __restrict__ cnt)
{
    int wv = threadIdx.x >> 6, lane = threadIdx.x & 63;
    int t = blockIdx.x * 4 + wv;
    const float* xr = x + (size_t)t * DM;
    float a0=0,a1=0,a2=0,a3=0,a4=0,a5=0,a6=0,a7=0;
    for (int d = lane; d < DM; d += 64) {
        float xv = xr[d];
        const float4* wp = (const float4*)(Wr + d * 8);
        float4 w0 = wp[0], w1 = wp[1];
        a0 += xv * w0.x; a1 += xv * w0.y; a2 += xv * w0.z; a3 += xv * w0.w;
        a4 += xv * w1.x; a5 += xv * w1.y; a6 += xv * w1.z; a7 += xv * w1.w;
    }
#pragma unroll
    for (int off = 32; off; off >>= 1) {
        a0 += __shfl_xor(a0, off); a1 += __shfl_xor(a1, off);
        a2 += __shfl_xor(a2, off); a3 += __shfl_xor(a3, off);
        a4 += __shfl_xor(a4, off); a5 += __shfl_xor(a5, off);
        a6 += __shfl_xor(a6, off); a7 += __shfl_xor(a7, off);
    }
    if (lane == 0) {
        float l[8] = {a0 + br[0], a1 + br[1], a2 + br[2], a3 + br[3],
                      a4 + br[4], a5 + br[5], a6 + br[6], a7 + br[7]};
        int i0 = 0;
#pragma unroll
        for (int e = 1; e < 8; e++) if (l[e] > l[i0]) i0 = e;
        int i1 = (i0 == 0) ? 1 : 0;
#pragma unroll
        for (int e = 0; e < 8; e++) if (e != i0 && l[e] > l[i1]) i1 = e;
        float p1 = expf(l[i1] - l[i0]);
        float s = 1.0f + p1;
        topk_idx[2 * t]     = i0;
        topk_idx[2 * t + 1] = i1;
        topk_p[2 * t]       = 1.0f / s;
        topk_p[2 * t + 1]   = p1 / s;
        atomicAdd(&cnt[i0], 1);
        atomicAdd(&cnt[i1], 1);
    }
}

__global__ void k_scan(const int* __restrict__ cnt, int* __restrict__ offs, int* __restrict__ fill) {
    if (threadIdx.x == 0) {
        int s = 0;
        for (int e = 0; e < E_N; e++) { offs[e] = s; fill[e] = s; s += cnt[e]; }
        offs[E_N] = s;
    }
}

__global__ void k_scatter(const int* __restrict__ topk_idx, int* __restrict__ fill,
                          int* __restrict__ assign_tok, int* __restrict__ assign_e,
                          int* __restrict__ slot) {
    int t = blockIdx.x * blockDim.x + threadIdx.x;
    if (t >= NTOK) return;
#pragma unroll
    for (int k = 0; k < TOPK; k++) {
        int e = topk_idx[2 * t + k];
        int pos = atomicAdd(&fill[e], 1);
        assign_tok[pos] = t;
        assign_e[pos] = e;
        slot[2 * t + k] = pos;
    }
}

// ---------------- grouped GEMM, 256xBNt tile, 8 waves, dbuf 2-phase ----------
// C[off_e+m][n] = relu(sum_k A[row(m)][k]*BT[e][n][k] + bias[e][n]), m<cnt[e].
// Expert->XCD pinning: bid&7 = e, so one expert's A rows stay in one XCD's L2.
// LDS double buffer, XOR swizzle phys_byte = log_byte ^ ((row&7)<<4); staged by
// global_load_lds with inverse-swizzled global source column.
// Schedule per K-step: stage(next) -> ds_read(cur) -> MFMA -> __syncthreads().

template<int BNt>
__global__ __launch_bounds__(512, 1) void k_gemm256(
    const unsigned short* __restrict__ A,
    const unsigned short* __restrict__ BT,
    const float* __restrict__ bias,
    unsigned short* __restrict__ C,
    const int* __restrict__ cnt, const int* __restrict__ offs,
    const int* __restrict__ gather_tok,
    int K, int N, int ldA, int GY)
{
    constexpr int NF = BNt / 64;     // B frags per wave: 4 (BNt=256) or 2 (BNt=128)
    constexpr int WN = BNt / 4;      // wave N extent

    __shared__ __align__(1024) char lds[2][32768 + BNt * 128];

    int bid = blockIdx.x;
    int e = bid & 7;                 // expert == XCD
    int slot = bid >> 3;
    int xn = slot / GY, y = slot - xn * GY;   // y-inner: consecutive blocks share B panel

    int M = cnt[e];
    int m0 = y * 256;
    if (m0 >= M) return;
    int n0 = xn * BNt;
    int off_e = offs[e];
    int tid = threadIdx.x;
    int wv = tid >> 6, lane = tid & 63;
    int lr = lane & 15, hi = lane >> 4;
    int wr = wv >> 2, wc = wv & 3;

    // staging pointers: instr j covers rows j*8+(lane>>3), 16B at swizzled col
    int colsw = ((lane & 7) ^ (lane >> 3)) * 8;
    const unsigned short* aptr[4];
    const unsigned short* bptr[NF];
#pragma unroll
    for (int i = 0; i < 4; i++) {
        int j = wv * 4 + i;
        int r = m0 + j * 8 + (lane >> 3); r = (r < M) ? r : (M - 1);
        size_t arow = gather_tok ? (size_t)gather_tok[off_e + r] : (size_t)(off_e + r);
        aptr[i] = A + arow * (size_t)ldA + colsw;
    }
#pragma unroll
    for (int i = 0; i < NF; i++) {
        int j = wv * NF + i;
        int r = n0 + j * 8 + (lane >> 3);
        bptr[i] = BT + ((size_t)e * N + r) * (size_t)K + colsw;
    }

    f32x4 acc[8][NF];
    f32x4 zz = {0.f, 0.f, 0.f, 0.f};
#pragma unroll
    for (int mi = 0; mi < 8; mi++)
#pragma unroll
        for (int ni = 0; ni < NF; ni++) acc[mi][ni] = zz;

    auto stage = [&](char* dst, int kof) {
#pragma unroll
        for (int i = 0; i < 4; i++)
            gload16(aptr[i] + kof, (unsigned short*)(dst + (wv * 4 + i) * 1024));
#pragma unroll
        for (int i = 0; i < NF; i++)
            gload16(bptr[i] + kof, (unsigned short*)(dst + 32768 + (wv * NF + i) * 1024));
    };

    int nt = K >> 6;
    stage(lds[0], 0);
    __syncthreads();

    for (int t = 0; t < nt; ++t) {
        char* cur = lds[t & 1];
        char* nxt = lds[(t + 1) & 1];
        if (t + 1 < nt) stage(nxt, (t + 1) * 64);
#pragma unroll
        for (int ks = 0; ks < 2; ks++) {
            int cb = (ks * 64 + hi * 16) ^ ((lr & 7) << 4);
            short8 bfr[NF], afr[8];
#pragma unroll
            for (int ni = 0; ni < NF; ni++)
                bfr[ni] = *(const short8*)(cur + 32768 + (wc * WN + ni * 16 + lr) * 128 + cb);
#pragma unroll
            for (int mi = 0; mi < 8; mi++)
                afr[mi] = *(const short8*)(cur + (wr * 128 + mi * 16 + lr) * 128 + cb);
            __builtin_amdgcn_s_setprio(1);
#pragma unroll
            for (int mi = 0; mi < 8; mi++)
#pragma unroll
                for (int ni = 0; ni < NF; ni++)
                    acc[mi][ni] = __builtin_amdgcn_mfma_f32_16x16x32_bf16(
                        afr[mi], bfr[ni], acc[mi][ni], 0, 0, 0);
            __builtin_amdgcn_s_setprio(0);
        }
        __syncthreads();   // drains vmcnt (next tile staged) + lgkmcnt, then barrier
    }

    // epilogue: bias + relu + bf16 store
    float bv[NF];
#pragma unroll
    for (int ni = 0; ni < NF; ni++)
        bv[ni] = bias[(size_t)e * N + (n0 + wc * WN + ni * 16 + lr)];
#pragma unroll
    for (int mi = 0; mi < 8; mi++) {
        int mb = m0 + wr * 128 + mi * 16 + hi * 4;
#pragma unroll
        for (int r = 0; r < 4; r++) {
            int m = mb + r;
            if (m < M) {
                unsigned short* crow = C + (size_t)(off_e + m) * N;
#pragma unroll
                for (int ni = 0; ni < NF; ni++) {
                    float v = fmaxf(acc[mi][ni][r] + bv[ni], 0.0f);
                    crow[n0 + wc * WN + ni * 16 + lr] = f2bf(v);
                }
            }
        }
    }
}

// ---------------- LN1 over F, in-place ----------------

__global__ __launch_bounds__(256) void k_ln1(unsigned short* __restrict__ H,
        const float* __restrict__ g, const float* __restrict__ b,
        const int* __restrict__ assign_e)
{
    size_t a = blockIdx.x;
    int e = assign_e[a];
    unsigned short* row = H + a * FF;
    int tid = threadIdx.x;
    uint4 u0 = *(const uint4*)(row + tid * 16);
    uint4 u1 = *(const uint4*)(row + tid * 16 + 8);
    float v[16];
    unp(u0.x, v[0], v[1]);  unp(u0.y, v[2], v[3]);
    unp(u0.z, v[4], v[5]);  unp(u0.w, v[6], v[7]);
    unp(u1.x, v[8], v[9]);  unp(u1.y, v[10], v[11]);
    unp(u1.z, v[12], v[13]); unp(u1.w, v[14], v[15]);
    float s = 0.f, q = 0.f;
#pragma unroll
    for (int i = 0; i < 16; i++) { s += v[i]; q += v[i] * v[i]; }
#pragma unroll
    for (int off = 32; off; off >>= 1) { s += __shfl_xor(s, off); q += __shfl_xor(q, off); }
    __shared__ float red[8];
    int wv = tid >> 6, lane = tid & 63;
    if (lane == 0) { red[wv * 2] = s; red[wv * 2 + 1] = q; }
    __syncthreads();
    s = red[0] + red[2] + red[4] + red[6];
    q = red[1] + red[3] + red[5] + red[7];
    float mu = s * (1.0f / FF);
    float var = q * (1.0f / FF) - mu * mu;
    float rstd = rsqrtf(var + LN_EPS);
    const float* gg = g + (size_t)e * FF + tid * 16;
    const float* bb = b + (size_t)e * FF + tid * 16;
    float4 G0 = *(const float4*)(gg);      float4 G1 = *(const float4*)(gg + 4);
    float4 G2 = *(const float4*)(gg + 8);  float4 G3 = *(const float4*)(gg + 12);
    float4 B0 = *(const float4*)(bb);      float4 B1 = *(const float4*)(bb + 4);
    float4 B2 = *(const float4*)(bb + 8);  float4 B3 = *(const float4*)(bb + 12);
    float gvv[16] = {G0.x,G0.y,G0.z,G0.w,G1.x,G1.y,G1.z,G1.w,G2.x,G2.y,G2.z,G2.w,G3.x,G3.y,G3.z,G3.w};
    float bvv[16] = {B0.x,B0.y,B0.z,B0.w,B1.x,B1.y,B1.z,B1.w,B2.x,B2.y,B2.z,B2.w,B3.x,B3.y,B3.z,B3.w};
#pragma unroll
    for (int i = 0; i < 16; i++) v[i] = (v[i] - mu) * rstd * gvv[i] + bvv[i];
    u0.x = pk(v[0], v[1]);  u0.y = pk(v[2], v[3]);
    u0.z = pk(v[4], v[5]);  u0.w = pk(v[6], v[7]);
    u1.x = pk(v[8], v[9]);  u1.y = pk(v[10], v[11]);
    u1.z = pk(v[12], v[13]); u1.w = pk(v[14], v[15]);
    *(uint4*)(row + tid * 16) = u0;
    *(uint4*)(row + tid * 16 + 8) = u1;
}

// ---------------- LN2 + gated combine ----------------

__global__ __launch_bounds__(256) void k_comb(const unsigned short* __restrict__ Y,
        const float* __restrict__ g, const float* __restrict__ b,
        const int* __restrict__ slot, const float* __restrict__ topk_p,
        const int* __restrict__ assign_e, float* __restrict__ out)
{
    int t = blockIdx.x;
    int s0 = slot[2 * t], s1 = slot[2 * t + 1];
    float p0 = topk_p[2 * t], p1 = topk_p[2 * t + 1];
    int e0 = assign_e[s0], e1 = assign_e[s1];
    int tid = threadIdx.x;
    uint2 ua = *(const uint2*)(Y + (size_t)s0 * DM + tid * 4);
    uint2 ub = *(const uint2*)(Y + (size_t)s1 * DM + tid * 4);
    float va[4], vb[4];
    unp(ua.x, va[0], va[1]); unp(ua.y, va[2], va[3]);
    unp(ub.x, vb[0], vb[1]); unp(ub.y, vb[2], vb[3]);
    float sa = 0.f, qa = 0.f, sb = 0.f, qb = 0.f;
#pragma unroll
    for (int i = 0; i < 4; i++) {
        sa += va[i]; qa += va[i] * va[i];
        sb += vb[i]; qb += vb[i] * vb[i];
    }
#pragma unroll
    for (int off = 32; off; off >>= 1) {
        sa += __shfl_xor(sa, off); qa += __shfl_xor(qa, off);
        sb += __shfl_xor(sb, off); qb += __shfl_xor(qb, off);
    }
    __shared__ float red[16];
    int wv = tid >> 6, lane = tid & 63;
    if (lane == 0) { red[wv*4+0]=sa; red[wv*4+1]=qa; red[wv*4+2]=sb; red[wv*4+3]=qb; }
    __syncthreads();
    sa = red[0] + red[4] + red[8]  + red[12];
    qa = red[1] + red[5] + red[9]  + red[13];
    sb = red[2] + red[6] + red[10] + red[14];
    qb = red[3] + red[7] + red[11] + red[15];
    float mua = sa * (1.0f / DM), vara = qa * (1.0f / DM) - mua * mua;
    float ra = rsqrtf(vara + LN_EPS);
    float mub = sb * (1.0f / DM), varb = qb * (1.0f / DM) - mub * mub;
    float rb = rsqrtf(varb + LN_EPS);
    int d = tid * 4;
    float4 ga  = *(const float4*)(g + (size_t)e0 * DM + d);
    float4 ba  = *(const float4*)(b + (size_t)e0 * DM + d);
    float4 gb4 = *(const float4*)(g + (size_t)e1 * DM + d);
    float4 bb4 = *(const float4*)(b + (size_t)e1 * DM + d);
    float4 o;
    o.x = p0 * ((va[0] - mua) * ra * ga.x + ba.x) + p1 * ((vb[0] - mub) * rb * gb4.x + bb4.x);
    o.y = p0 * ((va[1] - mua) * ra * ga.y + ba.y) + p1 * ((vb[1] - mub) * rb * gb4.y + bb4.y);
    o.z = p0 * ((va[2] - mua) * ra * ga.z + ba.z) + p1 * ((vb[2] - mub) * rb * gb4.z + bb4.z);
    o.w = p0 * ((va[3] - mua) * ra * ga.w + ba.w) + p1 * ((vb[3] - mub) * rb * gb4.w + bb4.w);
    *(float4*)(out + (size_t)t * DM + d) = o;
}

// ---------------- launch ----------------

extern "C" void kernel_launch(void* const* d_in, const int* in_sizes, int n_in,
                              void* d_out, int out_size, void* d_ws, size_t ws_size,
                              hipStream_t stream) {
    const float* x   = (const float*)d_in[0];
    const float* Wr  = (const float*)d_in[1];
    const float* br  = (const float*)d_in[2];
    const float* W1  = (const float*)d_in[3];
    const float* b1  = (const float*)d_in[4];
    const float* g1  = (const float*)d_in[5];
    const float* be1 = (const float*)d_in[6];
    const float* W2  = (const float*)d_in[7];
    const float* b2  = (const float*)d_in[8];
    const float* g2  = (const float*)d_in[9];
    const float* be2 = (const float*)d_in[10];
    float* out = (float*)d_out;

    char* w = (char*)d_ws;
    int*   cnt        = (int*)(w);
    int*   fill       = (int*)(w + 64);
    int*   offs       = (int*)(w + 128);
    int*   topk_idx   = (int*)(w + 512);
    float* topk_p     = (float*)(w + 512 + (32 << 10));
    int*   assign_tok = (int*)(w + 512 + (64 << 10));
    int*   assign_e   = (int*)(w + 512 + (96 << 10));
    int*   slot       = (int*)(w + 512 + (128 << 10));
    unsigned short* xb  = (unsigned short*)(w + ((size_t)1 << 20));
    unsigned short* W1T = (unsigned short*)(w + ((size_t)9 << 20));    // [E][F][D] bf16
    unsigned short* W2T = (unsigned short*)(w + ((size_t)73 << 20));   // [E][D][F] bf16
    unsigned short* Hb  = (unsigned short*)(w + ((size_t)137 << 20));  // [NA][F] bf16
    unsigned short* Yb  = (unsigned short*)(w + ((size_t)201 << 20));  // [NA][D] bf16

    k_zero<<<1, 64, 0, stream>>>((int*)w);
    k_conv_bf16<<<(NTOK * DM / 4 + 255) / 256, 256, 0, stream>>>(x, xb, NTOK * DM / 4);
    k_transpose_bf16<<<dim3(FF / 64, DM / 64, E_N), 256, 0, stream>>>(W1, W1T, DM, FF);
    k_transpose_bf16<<<dim3(DM / 64, FF / 64, E_N), 256, 0, stream>>>(W2, W2T, FF, DM);
    k_router<<<NTOK / 4, 256, 0, stream>>>(x, Wr, br, topk_idx, topk_p, cnt);
    k_scan<<<1, 64, 0, stream>>>(cnt, offs, fill);
    k_scatter<<<NTOK / 256, 256, 0, stream>>>(topk_idx, fill, assign_tok, assign_e, slot);
    // GEMM1: [NA rows] x W1T -> Hb ; N=FF, K=DM. grid = 8 xcd * GY(16) * XN(16)
    k_gemm256<256><<<8 * 16 * 16, 512, 0, stream>>>(
        xb, W1T, b1, Hb, cnt, offs, assign_tok, DM, FF, DM, 16);
    k_ln1<<<NA, 256, 0, stream>>>(Hb, g1, be1, assign_e);
    // GEMM2: Hb x W2T -> Yb ; N=DM, K=FF ; BNt=128 -> XN=8
    k_gemm256<128><<<8 * 16 * 8, 512, 0, stream>>>(
        Hb, W2T, b2, Yb, cnt, offs, nullptr, FF, DM, FF, 16);
    k_comb<<<NTOK, 256, 0, stream>>>(Yb, g2, be2, slot, topk_p, assign_e, out);
}

// Round 5
// 513.549 us; speedup vs baseline: 1.0438x; 1.0438x over previous
//
#include <hip/hip_runtime.h>

// Mixture-of-Experts, sparse top-2.
// Round 5: 128x128 double-buffered 2-phase grouped GEMM (2 blocks/CU),
// expert->XCD pinning, XOR-swizzled LDS via global_load_lds(16B),
// router fused with f32->bf16 conversion of x.

#define E_N 8
#define TOPK 2
#define DM 1024
#define FF 4096
#define NTOK 4096
#define NA 8192
#define LN_EPS 1e-5f

typedef __attribute__((ext_vector_type(4))) float f32x4;
typedef __attribute__((ext_vector_type(8))) short short8;

__device__ __forceinline__ unsigned short f2bf(float f) {
    unsigned int u = __builtin_bit_cast(unsigned int, f);
    u = (u + 0x7FFFu + ((u >> 16) & 1u)) >> 16;   // RNE
    return (unsigned short)u;
}
__device__ __forceinline__ float bf2f(unsigned short h) {
    unsigned int u = ((unsigned int)h) << 16;
    return __builtin_bit_cast(float, u);
}
__device__ __forceinline__ void unp(unsigned int u, float& lo, float& hi) {
    lo = bf2f((unsigned short)(u & 0xffffu));
    hi = bf2f((unsigned short)(u >> 16));
}
__device__ __forceinline__ unsigned int pk(float lo, float hi) {
    return (unsigned int)f2bf(lo) | ((unsigned int)f2bf(hi) << 16);
}

__device__ __forceinline__ void gload16(const unsigned short* g, unsigned short* lds) {
    __builtin_amdgcn_global_load_lds(
        (const __attribute__((address_space(1))) unsigned int*)g,
        (__attribute__((address_space(3))) unsigned int*)lds, 16, 0, 0);
}

// ---------------- small utility kernels ----------------

__global__ void k_zero(int* p) { p[threadIdx.x] = 0; }

// [E][R][C] f32 -> [E][C][R] bf16, 64x64 tile. Conflict-free LDS, 16B stores.
__global__ __launch_bounds__(256) void k_transpose_bf16(const float* __restrict__ src,
        unsigned short* __restrict__ dst, int R, int C) {
    __shared__ float tile[64][65];
    size_t e = blockIdx.z;
    const float* s = src + e * (size_t)R * C + (size_t)(blockIdx.y * 64) * C + blockIdx.x * 64;
    unsigned short* d = dst + e * (size_t)R * C + (size_t)(blockIdx.x * 64) * R + blockIdx.y * 64;
    int tid = threadIdx.x;
    int lr = tid >> 4, lc = (tid & 15) * 4;
#pragma unroll
    for (int p = 0; p < 4; p++) {
        float4 v = *(const float4*)(s + (size_t)(lr + p * 16) * C + lc);
        tile[lr + p * 16][lc] = v.x;     tile[lr + p * 16][lc + 1] = v.y;
        tile[lr + p * 16][lc + 2] = v.z; tile[lr + p * 16][lc + 3] = v.w;
    }
    __syncthreads();
    int rc = (tid & 7) * 8;
#pragma unroll
    for (int p = 0; p < 2; p++) {
        int cc = (tid >> 3) + p * 32;
        float a0 = tile[rc + 0][cc], a1 = tile[rc + 1][cc];
        float a2 = tile[rc + 2][cc], a3 = tile[rc + 3][cc];
        float a4 = tile[rc + 4][cc], a5 = tile[rc + 5][cc];
        float a6 = tile[rc + 6][cc], a7 = tile[rc + 7][cc];
        uint4 o;
        o.x = pk(a0, a1); o.y = pk(a2, a3); o.z = pk(a4, a5); o.w = pk(a6, a7);
        *(uint4*)(d + (size_t)cc * R + rc) = o;
    }
}

// ---------------- router (+ fused f32->bf16 conversion of x) ----------------

__global__ __launch_bounds__(256) void k_router(const float* __restrict__ x,
        const float* __restrict__ Wr, const float* __restrict__ br,
        unsigned short* __restrict__ xb,
        int* __restrict__ topk_idx, float* __restrict__ topk_p, int* __restrict__ cnt)
{
    int wv = threadIdx.x >> 6, lane = threadIdx.x & 63;
    int t = blockIdx.x * 4 + wv;
    const float* xr = x + (size_t)t * DM;
    unsigned short* xbr = xb + (size_t)t * DM;
    float a0=0,a1=0,a2=0,a3=0,a4=0,a5=0,a6=0,a7=0;
    for (int d = lane; d < DM; d += 64) {
        float xv = xr[d];
        xbr[d] = f2bf(xv);
        const float4* wp = (const float4*)(Wr + d * 8);
        float4 w0 = wp[0], w1 = wp[1];
        a0 += xv * w0.x; a1 += xv * w0.y; a2 += xv * w0.z; a3 += xv * w0.w;
        a4 += xv * w1.x; a5 += xv * w1.y; a6 += xv * w1.z; a7 += xv * w1.w;
    }
#pragma unroll
    for (int off = 32; off; off >>= 1) {
        a0 += __shfl_xor(a0, off); a1 += __shfl_xor(a1, off);
        a2 += __shfl_xor(a2, off); a3 += __shfl_xor(a3, off);
        a4 += __shfl_xor(a4, off); a5 += __shfl_xor(a5, off);
        a6 += __shfl_xor(a6, off); a7 += __shfl_xor(a7, off);
    }
    if (lane == 0) {
        float l[8] = {a0 + br[0], a1 + br[1], a2 + br[2], a3 + br[3],
                      a4 + br[4], a5 + br[5], a6 + br[6], a7 + br[7]};
        int i0 = 0;
#pragma unroll
        for (int e = 1; e < 8; e++) if (l[e] > l[i0]) i0 = e;
        int i1 = (i0 == 0) ? 1 : 0;
#pragma unroll
        for (int e = 0; e < 8; e++) if (e != i0 && l[e] > l[i1]) i1 = e;
        float p1 = expf(l[i1] - l[i0]);
        float s = 1.0f + p1;
        topk_idx[2 * t]     = i0;
        topk_idx[2 * t + 1] = i1;
        topk_p[2 * t]       = 1.0f / s;
        topk_p[2 * t + 1]   = p1 / s;
        atomicAdd(&cnt[i0], 1);
        atomicAdd(&cnt[i1], 1);
    }
}

__global__ void k_scan(const int* __restrict__ cnt, int* __restrict__ offs, int* __restrict__ fill) {
    if (threadIdx.x == 0) {
        int s = 0;
        for (int e = 0; e < E_N; e++) { offs[e] = s; fill[e] = s; s += cnt[e]; }
        offs[E_N] = s;
    }
}

__global__ void k_scatter(const int* __restrict__ topk_idx, int* __restrict__ fill,
                          int* __restrict__ assign_tok, int* __restrict__ assign_e,
                          int* __restrict__ slot) {
    int t = blockIdx.x * blockDim.x + threadIdx.x;
    if (t >= NTOK) return;
#pragma unroll
    for (int k = 0; k < TOPK; k++) {
        int e = topk_idx[2 * t + k];
        int pos = atomicAdd(&fill[e], 1);
        assign_tok[pos] = t;
        assign_e[pos] = e;
        slot[2 * t + k] = pos;
    }
}

// ---------------- grouped GEMM, 128x128 tile, 4 waves, dbuf 2-phase ---------
// C[off_e+m][n] = relu(sum_k A[row(m)][k]*BT[e][n][k] + bias[e][n]), m<cnt[e].
// Expert->XCD pinning: bid&7 = e. LDS double buffer 2x32KB (2 blocks/CU),
// XOR swizzle phys_byte = log_byte ^ ((row&7)<<4), staged by global_load_lds
// with inverse-swizzled global source column.
// Per K-step: stage(next) -> ds_read(cur) -> MFMA -> __syncthreads().

__global__ __launch_bounds__(256, 2) void k_gemm128(
    const unsigned short* __restrict__ A,
    const unsigned short* __restrict__ BT,
    const float* __restrict__ bias,
    unsigned short* __restrict__ C,
    const int* __restrict__ cnt, const int* __restrict__ offs,
    const int* __restrict__ gather_tok,
    int K, int N, int ldA, int GY)
{
    __shared__ __align__(1024) char lds[2][32768];   // [buf][A 16K | B 16K]

    int bid = blockIdx.x;
    int e = bid & 7;                          // expert == XCD
    int slot = bid >> 3;
    int xn = slot / GY, y = slot - xn * GY;   // y-inner: same B panel consecutive

    int M = cnt[e];
    int m0 = y * 128;
    if (m0 >= M) return;
    int n0 = xn * 128;
    int off_e = offs[e];
    int tid = threadIdx.x;
    int wv = tid >> 6, lane = tid & 63;
    int lr = lane & 15, hi = lane >> 4;
    int mW = (wv >> 1) * 64, nW = (wv & 1) * 64;

    // staging: A,B each 16 x 1KB instrs; wave wv does j = wv*4+i.
    // instr j covers rows j*8+(lane>>3), 16B at inverse-swizzled col.
    int colsw = ((lane & 7) ^ (lane >> 3)) * 8;
    const unsigned short* aptr[4];
    const unsigned short* bptr[4];
#pragma unroll
    for (int i = 0; i < 4; i++) {
        int j = wv * 4 + i;
        int r = m0 + j * 8 + (lane >> 3); r = (r < M) ? r : (M - 1);
        size_t arow = gather_tok ? (size_t)gather_tok[off_e + r] : (size_t)(off_e + r);
        aptr[i] = A + arow * (size_t)ldA + colsw;
        int rb = n0 + j * 8 + (lane >> 3);
        bptr[i] = BT + ((size_t)e * N + rb) * (size_t)K + colsw;
    }

    f32x4 acc[4][4];
    f32x4 zz = {0.f, 0.f, 0.f, 0.f};
#pragma unroll
    for (int mi = 0; mi < 4; mi++)
#pragma unroll
        for (int ni = 0; ni < 4; ni++) acc[mi][ni] = zz;

    auto stage = [&](char* dst, int kof) {
#pragma unroll
        for (int i = 0; i < 4; i++) {
            gload16(aptr[i] + kof, (unsigned short*)(dst + (wv * 4 + i) * 1024));
            gload16(bptr[i] + kof, (unsigned short*)(dst + 16384 + (wv * 4 + i) * 1024));
        }
    };

    int nt = K >> 6;
    stage(lds[0], 0);
    __syncthreads();

    for (int t = 0; t < nt; ++t) {
        char* cur = lds[t & 1];
        char* nxt = lds[(t + 1) & 1];
        if (t + 1 < nt) stage(nxt, (t + 1) * 64);
#pragma unroll
        for (int ks = 0; ks < 2; ks++) {
            int cb = (ks * 64 + hi * 16) ^ ((lr & 7) << 4);
            short8 afr[4], bfr[4];
#pragma unroll
            for (int ni = 0; ni < 4; ni++)
                bfr[ni] = *(const short8*)(cur + 16384 + (nW + ni * 16 + lr) * 128 + cb);
#pragma unroll
            for (int mi = 0; mi < 4; mi++)
                afr[mi] = *(const short8*)(cur + (mW + mi * 16 + lr) * 128 + cb);
            __builtin_amdgcn_s_setprio(1);
#pragma unroll
            for (int mi = 0; mi < 4; mi++)
#pragma unroll
                for (int ni = 0; ni < 4; ni++)
                    acc[mi][ni] = __builtin_amdgcn_mfma_f32_16x16x32_bf16(
                        afr[mi], bfr[ni], acc[mi][ni], 0, 0, 0);
            __builtin_amdgcn_s_setprio(0);
        }
        __syncthreads();   // drains vmcnt (next tile) + lgkmcnt, then barrier
    }

    // epilogue: bias + relu + bf16 store
    float bv[4];
#pragma unroll
    for (int ni = 0; ni < 4; ni++)
        bv[ni] = bias[(size_t)e * N + (n0 + nW + ni * 16 + lr)];
#pragma unroll
    for (int mi = 0; mi < 4; mi++) {
        int mb = m0 + mW + mi * 16 + hi * 4;
#pragma unroll
        for (int r = 0; r < 4; r++) {
            int m = mb + r;
            if (m < M) {
                unsigned short* crow = C + (size_t)(off_e + m) * N;
#pragma unroll
                for (int ni = 0; ni < 4; ni++) {
                    float v = fmaxf(acc[mi][ni][r] + bv[ni], 0.0f);
                    crow[n0 + nW + ni * 16 + lr] = f2bf(v);
                }
            }
        }
    }
}

// ---------------- LN1 over F, in-place ----------------

__global__ __launch_bounds__(256) void k_ln1(unsigned short* __restrict__ H,
        const float* __restrict__ g, const float* __restrict__ b,
        const int* __restrict__ assign_e)
{
    size_t a = blockIdx.x;
    int e = assign_e[a];
    unsigned short* row = H + a * FF;
    int tid = threadIdx.x;
    uint4 u0 = *(const uint4*)(row + tid * 16);
    uint4 u1 = *(const uint4*)(row + tid * 16 + 8);
    float v[16];
    unp(u0.x, v[0], v[1]);  unp(u0.y, v[2], v[3]);
    unp(u0.z, v[4], v[5]);  unp(u0.w, v[6], v[7]);
    unp(u1.x, v[8], v[9]);  unp(u1.y, v[10], v[11]);
    unp(u1.z, v[12], v[13]); unp(u1.w, v[14], v[15]);
    float s = 0.f, q = 0.f;
#pragma unroll
    for (int i = 0; i < 16; i++) { s += v[i]; q += v[i] * v[i]; }
#pragma unroll
    for (int off = 32; off; off >>= 1) { s += __shfl_xor(s, off); q += __shfl_xor(q, off); }
    __shared__ float red[8];
    int wv = tid >> 6, lane = tid & 63;
    if (lane == 0) { red[wv * 2] = s; red[wv * 2 + 1] = q; }
    __syncthreads();
    s = red[0] + red[2] + red[4] + red[6];
    q = red[1] + red[3] + red[5] + red[7];
    float mu = s * (1.0f / FF);
    float var = q * (1.0f / FF) - mu * mu;
    float rstd = rsqrtf(var + LN_EPS);
    const float* gg = g + (size_t)e * FF + tid * 16;
    const float* bb = b + (size_t)e * FF + tid * 16;
    float4 G0 = *(const float4*)(gg);      float4 G1 = *(const float4*)(gg + 4);
    float4 G2 = *(const float4*)(gg + 8);  float4 G3 = *(const float4*)(gg + 12);
    float4 B0 = *(const float4*)(bb);      float4 B1 = *(const float4*)(bb + 4);
    float4 B2 = *(const float4*)(bb + 8);  float4 B3 = *(const float4*)(bb + 12);
    float gvv[16] = {G0.x,G0.y,G0.z,G0.w,G1.x,G1.y,G1.z,G1.w,G2.x,G2.y,G2.z,G2.w,G3.x,G3.y,G3.z,G3.w};
    float bvv[16] = {B0.x,B0.y,B0.z,B0.w,B1.x,B1.y,B1.z,B1.w,B2.x,B2.y,B2.z,B2.w,B3.x,B3.y,B3.z,B3.w};
#pragma unroll
    for (int i = 0; i < 16; i++) v[i] = (v[i] - mu) * rstd * gvv[i] + bvv[i];
    u0.x = pk(v[0], v[1]);  u0.y = pk(v[2], v[3]);
    u0.z = pk(v[4], v[5]);  u0.w = pk(v[6], v[7]);
    u1.x = pk(v[8], v[9]);  u1.y = pk(v[10], v[11]);
    u1.z = pk(v[12], v[13]); u1.w = pk(v[14], v[15]);
    *(uint4*)(row + tid * 16) = u0;
    *(uint4*)(row + tid * 16 + 8) = u1;
}

// ---------------- LN2 + gated combine ----------------

__global__ __launch_bounds__(256) void k_comb(const unsigned short* __restrict__ Y,
        const float* __restrict__ g, const float* __restrict__ b,
        const int* __restrict__ slot, const float* __restrict__ topk_p,
        const int* __restrict__ assign_e, float* __restrict__ out)
{
    int t = blockIdx.x;
    int s0 = slot[2 * t], s1 = slot[2 * t + 1];
    float p0 = topk_p[2 * t], p1 = topk_p[2 * t + 1];
    int e0 = assign_e[s0], e1 = assign_e[s1];
    int tid = threadIdx.x;
    uint2 ua = *(const uint2*)(Y + (size_t)s0 * DM + tid * 4);
    uint2 ub = *(const uint2*)(Y + (size_t)s1 * DM + tid * 4);
    float va[4], vb[4];
    unp(ua.x, va[0], va[1]); unp(ua.y, va[2], va[3]);
    unp(ub.x, vb[0], vb[1]); unp(ub.y, vb[2], vb[3]);
    float sa = 0.f, qa = 0.f, sb = 0.f, qb = 0.f;
#pragma unroll
    for (int i = 0; i < 4; i++) {
        sa += va[i]; qa += va[i] * va[i];
        sb += vb[i]; qb += vb[i] * vb[i];
    }
#pragma unroll
    for (int off = 32; off; off >>= 1) {
        sa += __shfl_xor(sa, off); qa += __shfl_xor(qa, off);
        sb += __shfl_xor(sb, off); qb += __shfl_xor(qb, off);
    }
    __shared__ float red[16];
    int wv = tid >> 6, lane = tid & 63;
    if (lane == 0) { red[wv*4+0]=sa; red[wv*4+1]=qa; red[wv*4+2]=sb; red[wv*4+3]=qb; }
    __syncthreads();
    sa = red[0] + red[4] + red[8]  + red[12];
    qa = red[1] + red[5] + red[9]  + red[13];
    sb = red[2] + red[6] + red[10] + red[14];
    qb = red[3] + red[7] + red[11] + red[15];
    float mua = sa * (1.0f / DM), vara = qa * (1.0f / DM) - mua * mua;
    float ra = rsqrtf(vara + LN_EPS);
    float mub = sb * (1.0f / DM), varb = qb * (1.0f / DM) - mub * mub;
    float rb = rsqrtf(varb + LN_EPS);
    int d = tid * 4;
    float4 ga  = *(const float4*)(g + (size_t)e0 * DM + d);
    float4 ba  = *(const float4*)(b + (size_t)e0 * DM + d);
    float4 gb4 = *(const float4*)(g + (size_t)e1 * DM + d);
    float4 bb4 = *(const float4*)(b + (size_t)e1 * DM + d);
    float4 o;
    o.x = p0 * ((va[0] - mua) * ra * ga.x + ba.x) + p1 * ((vb[0] - mub) * rb * gb4.x + bb4.x);
    o.y = p0 * ((va[1] - mua) * ra * ga.y + ba.y) + p1 * ((vb[1] - mub) * rb * gb4.y + bb4.y);
    o.z = p0 * ((va[2] - mua) * ra * ga.z + ba.z) + p1 * ((vb[2] - mub) * rb * gb4.z + bb4.z);
    o.w = p0 * ((va[3] - mua) * ra * ga.w + ba.w) + p1 * ((vb[3] - mub) * rb * gb4.w + bb4.w);
    *(float4*)(out + (size_t)t * DM + d) = o;
}

// ---------------- launch ----------------

extern "C" void kernel_launch(void* const* d_in, const int* in_sizes, int n_in,
                              void* d_out, int out_size, void* d_ws, size_t ws_size,
                              hipStream_t stream) {
    const float* x   = (const float*)d_in[0];
    const float* Wr  = (const float*)d_in[1];
    const float* br  = (const float*)d_in[2];
    const float* W1  = (const float*)d_in[3];
    const float* b1  = (const float*)d_in[4];
    const float* g1  = (const float*)d_in[5];
    const float* be1 = (const float*)d_in[6];
    const float* W2  = (const float*)d_in[7];
    const float* b2  = (const float*)d_in[8];
    const float* g2  = (const float*)d_in[9];
    const float* be2 = (const float*)d_in[10];
    float* out = (float*)d_out;

    char* w = (char*)d_ws;
    int*   cnt        = (int*)(w);
    int*   fill       = (int*)(w + 64);
    int*   offs       = (int*)(w + 128);
    int*   topk_idx   = (int*)(w + 512);
    float* topk_p     = (float*)(w + 512 + (32 << 10));
    int*   assign_tok = (int*)(w + 512 + (64 << 10));
    int*   assign_e   = (int*)(w + 512 + (96 << 10));
    int*   slot       = (int*)(w + 512 + (128 << 10));
    unsigned short* xb  = (unsigned short*)(w + ((size_t)1 << 20));
    unsigned short* W1T = (unsigned short*)(w + ((size_t)9 << 20));    // [E][F][D] bf16
    unsigned short* W2T = (unsigned short*)(w + ((size_t)73 << 20));   // [E][D][F] bf16
    unsigned short* Hb  = (unsigned short*)(w + ((size_t)137 << 20));  // [NA][F] bf16
    unsigned short* Yb  = (unsigned short*)(w + ((size_t)201 << 20));  // [NA][D] bf16

    k_zero<<<1, 64, 0, stream>>>((int*)w);
    k_transpose_bf16<<<dim3(FF / 64, DM / 64, E_N), 256, 0, stream>>>(W1, W1T, DM, FF);
    k_transpose_bf16<<<dim3(DM / 64, FF / 64, E_N), 256, 0, stream>>>(W2, W2T, FF, DM);
    k_router<<<NTOK / 4, 256, 0, stream>>>(x, Wr, br, xb, topk_idx, topk_p, cnt);
    k_scan<<<1, 64, 0, stream>>>(cnt, offs, fill);
    k_scatter<<<NTOK / 256, 256, 0, stream>>>(topk_idx, fill, assign_tok, assign_e, slot);
    // GEMM1: [NA rows] x W1T -> Hb ; N=FF, K=DM. grid = 8 xcd * (FF/128=32 xn) * 32 y
    k_gemm128<<<8 * 32 * 32, 256, 0, stream>>>(
        xb, W1T, b1, Hb, cnt, offs, assign_tok, DM, FF, DM, 32);
    k_ln1<<<NA, 256, 0, stream>>>(Hb, g1, be1, assign_e);
    // GEMM2: Hb x W2T -> Yb ; N=DM, K=FF. grid = 8 xcd * (DM/128=8 xn) * 32 y
    k_gemm128<<<8 * 8 * 32, 256, 0, stream>>>(
        Hb, W2T, b2, Yb, cnt, offs, nullptr, FF, DM, FF, 32);
    k_comb<<<NTOK, 256, 0, stream>>>(Yb, g2, be2, slot, topk_p, assign_e, out);
}

// Round 6
// 374.377 us; speedup vs baseline: 1.4319x; 1.3717x over previous
//
#include <hip/hip_runtime.h>

// Mixture-of-Experts, sparse top-2.
// Round 6: m97-exact single-buffer grouped GEMM (32KB LDS, 4-5 blocks/CU),
// expert->XCD pinning, split-K GEMM2, fused prep (transposes+router),
// single-block route (hist+scan+scatter). 6 launches total.

#define E_N 8
#define TOPK 2
#define DM 1024
#define FF 4096
#define NTOK 4096
#define NA 8192
#define LN_EPS 1e-5f

typedef __attribute__((ext_vector_type(4))) float f32x4;
typedef __attribute__((ext_vector_type(8))) short short8;

__device__ __forceinline__ unsigned short f2bf(float f) {
    unsigned int u = __builtin_bit_cast(unsigned int, f);
    u = (u + 0x7FFFu + ((u >> 16) & 1u)) >> 16;   // RNE
    return (unsigned short)u;
}
__device__ __forceinline__ float bf2f(unsigned short h) {
    unsigned int u = ((unsigned int)h) << 16;
    return __builtin_bit_cast(float, u);
}
__device__ __forceinline__ void unp(unsigned int u, float& lo, float& hi) {
    lo = bf2f((unsigned short)(u & 0xffffu));
    hi = bf2f((unsigned short)(u >> 16));
}
__device__ __forceinline__ unsigned int pk(float lo, float hi) {
    return (unsigned int)f2bf(lo) | ((unsigned int)f2bf(hi) << 16);
}

__device__ __forceinline__ void gload16(const unsigned short* g, unsigned short* lds) {
    __builtin_amdgcn_global_load_lds(
        (const __attribute__((address_space(1))) unsigned int*)g,
        (__attribute__((address_space(3))) unsigned int*)lds, 16, 0, 0);
}

// ---------------- prep: W1/W2 transpose (z<16) + router & x->bf16 (z==16) ----

__global__ __launch_bounds__(256) void k_prep(
        const float* __restrict__ W1, const float* __restrict__ W2,
        unsigned short* __restrict__ W1T, unsigned short* __restrict__ W2T,
        const float* __restrict__ x, const float* __restrict__ Wr,
        const float* __restrict__ br, unsigned short* __restrict__ xb,
        int* __restrict__ topk_idx, float* __restrict__ topk_p)
{
    __shared__ float tile[64][65];
    int z = blockIdx.z;
    int tid = threadIdx.x;

    if (z == 16) {
        // ---- router: 4 tokens per block (one per wave), fused f32->bf16 of x
        int wv = tid >> 6, lane = tid & 63;
        int t = blockIdx.x * 4 + wv;
        const float* xr = x + (size_t)t * DM;
        unsigned short* xbr = xb + (size_t)t * DM;
        float a0=0,a1=0,a2=0,a3=0,a4=0,a5=0,a6=0,a7=0;
        for (int d = lane; d < DM; d += 64) {
            float xv = xr[d];
            xbr[d] = f2bf(xv);
            const float4* wp = (const float4*)(Wr + d * 8);
            float4 w0 = wp[0], w1 = wp[1];
            a0 += xv * w0.x; a1 += xv * w0.y; a2 += xv * w0.z; a3 += xv * w0.w;
            a4 += xv * w1.x; a5 += xv * w1.y; a6 += xv * w1.z; a7 += xv * w1.w;
        }
#pragma unroll
        for (int off = 32; off; off >>= 1) {
            a0 += __shfl_xor(a0, off); a1 += __shfl_xor(a1, off);
            a2 += __shfl_xor(a2, off); a3 += __shfl_xor(a3, off);
            a4 += __shfl_xor(a4, off); a5 += __shfl_xor(a5, off);
            a6 += __shfl_xor(a6, off); a7 += __shfl_xor(a7, off);
        }
        if (lane == 0) {
            float l[8] = {a0 + br[0], a1 + br[1], a2 + br[2], a3 + br[3],
                          a4 + br[4], a5 + br[5], a6 + br[6], a7 + br[7]};
            int i0 = 0;
#pragma unroll
            for (int e = 1; e < 8; e++) if (l[e] > l[i0]) i0 = e;
            int i1 = (i0 == 0) ? 1 : 0;
#pragma unroll
            for (int e = 0; e < 8; e++) if (e != i0 && l[e] > l[i1]) i1 = e;
            float p1 = expf(l[i1] - l[i0]);
            float s = 1.0f + p1;
            topk_idx[2 * t]     = i0;
            topk_idx[2 * t + 1] = i1;
            topk_p[2 * t]       = 1.0f / s;
            topk_p[2 * t + 1]   = p1 / s;
        }
        return;
    }

    // ---- transpose [R][C] f32 -> [C][R] bf16, 64x64 tiles
    const float* src; unsigned short* dst; int R, C, bx, by;
    if (z < 8) {
        R = DM; C = FF;
        src = W1 + (size_t)z * R * C;  dst = W1T + (size_t)z * R * C;
        bx = blockIdx.x & 63; by = blockIdx.x >> 6;
    } else {
        R = FF; C = DM;
        src = W2 + (size_t)(z - 8) * R * C;  dst = W2T + (size_t)(z - 8) * R * C;
        bx = blockIdx.x & 15; by = blockIdx.x >> 4;
    }
    const float* s = src + (size_t)(by * 64) * C + bx * 64;
    unsigned short* d = dst + (size_t)(bx * 64) * R + by * 64;
    int lr = tid >> 4, lc = (tid & 15) * 4;
#pragma unroll
    for (int p = 0; p < 4; p++) {
        float4 v = *(const float4*)(s + (size_t)(lr + p * 16) * C + lc);
        tile[lr + p * 16][lc] = v.x;     tile[lr + p * 16][lc + 1] = v.y;
        tile[lr + p * 16][lc + 2] = v.z; tile[lr + p * 16][lc + 3] = v.w;
    }
    __syncthreads();
    int rc = (tid & 7) * 8;
#pragma unroll
    for (int p = 0; p < 2; p++) {
        int cc = (tid >> 3) + p * 32;
        float a0 = tile[rc + 0][cc], a1 = tile[rc + 1][cc];
        float a2 = tile[rc + 2][cc], a3 = tile[rc + 3][cc];
        float a4 = tile[rc + 4][cc], a5 = tile[rc + 5][cc];
        float a6 = tile[rc + 6][cc], a7 = tile[rc + 7][cc];
        uint4 o;
        o.x = pk(a0, a1); o.y = pk(a2, a3); o.z = pk(a4, a5); o.w = pk(a6, a7);
        *(uint4*)(d + (size_t)cc * R + rc) = o;
    }
}

// ---------------- route: histogram + prefix + scatter, one block ------------

__global__ __launch_bounds__(256) void k_route2(const int* __restrict__ topk_idx,
        int* __restrict__ cnt, int* __restrict__ offs,
        int* __restrict__ assign_tok, int* __restrict__ assign_e,
        int* __restrict__ slot)
{
    __shared__ int h[8], base[8];
    int tid = threadIdx.x;
    if (tid < 8) h[tid] = 0;
    __syncthreads();
    int el[32];
#pragma unroll
    for (int i = 0; i < 32; i++) {
        int idx = tid * 32 + i;
        el[i] = topk_idx[idx];
        atomicAdd(&h[el[i]], 1);
    }
    __syncthreads();
    if (tid == 0) {
        int s = 0;
        for (int e = 0; e < E_N; e++) { offs[e] = s; cnt[e] = h[e]; base[e] = s; s += h[e]; }
        offs[E_N] = s;
    }
    __syncthreads();
    if (tid < 8) h[tid] = base[tid];
    __syncthreads();
#pragma unroll
    for (int i = 0; i < 32; i++) {
        int idx = tid * 32 + i;
        int e = el[i];
        int pos = atomicAdd(&h[e], 1);
        assign_tok[pos] = idx >> 1;
        assign_e[pos] = e;
        slot[idx] = pos;
    }
}

// ---------------- grouped GEMM, 128x128, 4 waves, single-buffer (m97) -------
// C[off_e+m][n] (+ks*slicePitch) = epi(sum_{k in slice} A[row(m)][k]*BT[e][n][k])
// Expert->XCD pinning: bid&7 = e. LDS 32KB single buffer -> 4-5 blocks/CU.
// XOR swizzle phys_byte = log_byte ^ ((row&7)<<4); staged by global_load_lds
// with inverse-swizzled global source column. 2 barriers per K-step (m97).

template<bool GATHER, bool EPI>
__global__ __launch_bounds__(256) void k_gemm(
    const unsigned short* __restrict__ A,
    const unsigned short* __restrict__ BT,
    const float* __restrict__ bias,
    unsigned short* __restrict__ C,
    const int* __restrict__ cnt, const int* __restrict__ offs,
    const int* __restrict__ gather_tok,
    int Kslice, int N, int ldA, int ldB, int GY, int GX, size_t slicePitch)
{
    __shared__ __align__(1024) char lds[32768];   // A 16KB | B 16KB

    int bid = blockIdx.x;
    int e = bid & 7;                          // expert == XCD
    int r = bid >> 3;
    int y = r % GY; r /= GY;
    int xn = r % GX;
    int ks = r / GX;

    int M = cnt[e];
    int m0 = y * 128;
    if (m0 >= M) return;
    int n0 = xn * 128;
    int off_e = offs[e];
    int kbase = ks * Kslice;
    int tid = threadIdx.x;
    int wv = tid >> 6, lane = tid & 63;
    int lr = lane & 15, hi = lane >> 4;
    int mW = (wv >> 1) * 64, nW = (wv & 1) * 64;

    int colsw = ((lane & 7) ^ (lane >> 3)) * 8;
    const unsigned short* aptr[4];
    const unsigned short* bptr[4];
#pragma unroll
    for (int i = 0; i < 4; i++) {
        int j = wv * 4 + i;
        int rr = m0 + j * 8 + (lane >> 3); rr = (rr < M) ? rr : (M - 1);
        size_t arow = GATHER ? (size_t)gather_tok[off_e + rr] : (size_t)(off_e + rr);
        aptr[i] = A + arow * (size_t)ldA + kbase + colsw;
        int rb = n0 + j * 8 + (lane >> 3);
        bptr[i] = BT + ((size_t)e * N + rb) * (size_t)ldB + kbase + colsw;
    }

    f32x4 acc[4][4];
    f32x4 zz = {0.f, 0.f, 0.f, 0.f};
#pragma unroll
    for (int mi = 0; mi < 4; mi++)
#pragma unroll
        for (int ni = 0; ni < 4; ni++) acc[mi][ni] = zz;

    int nt = Kslice >> 6;
    for (int t = 0; t < nt; ++t) {
        __syncthreads();                      // prev tile fully consumed
#pragma unroll
        for (int i = 0; i < 4; i++) {
            gload16(aptr[i] + t * 64, (unsigned short*)(lds + (wv * 4 + i) * 1024));
            gload16(bptr[i] + t * 64, (unsigned short*)(lds + 16384 + (wv * 4 + i) * 1024));
        }
        __syncthreads();                      // drains vmcnt before barrier
#pragma unroll
        for (int kss = 0; kss < 2; kss++) {
            int cb = (kss * 64 + hi * 16) ^ ((lr & 7) << 4);
            short8 afr[4], bfr[4];
#pragma unroll
            for (int ni = 0; ni < 4; ni++)
                bfr[ni] = *(const short8*)(lds + 16384 + (nW + ni * 16 + lr) * 128 + cb);
#pragma unroll
            for (int mi = 0; mi < 4; mi++)
                afr[mi] = *(const short8*)(lds + (mW + mi * 16 + lr) * 128 + cb);
            __builtin_amdgcn_s_setprio(1);
#pragma unroll
            for (int mi = 0; mi < 4; mi++)
#pragma unroll
                for (int ni = 0; ni < 4; ni++)
                    acc[mi][ni] = __builtin_amdgcn_mfma_f32_16x16x32_bf16(
                        afr[mi], bfr[ni], acc[mi][ni], 0, 0, 0);
            __builtin_amdgcn_s_setprio(0);
        }
    }

    unsigned short* Cs = C + ks * slicePitch;
    float bv[4] = {0.f, 0.f, 0.f, 0.f};
    if (EPI) {
#pragma unroll
        for (int ni = 0; ni < 4; ni++)
            bv[ni] = bias[(size_t)e * N + (n0 + nW + ni * 16 + lr)];
    }
#pragma unroll
    for (int mi = 0; mi < 4; mi++) {
        int mb = m0 + mW + mi * 16 + hi * 4;
#pragma unroll
        for (int rr = 0; rr < 4; rr++) {
            int m = mb + rr;
            if (m < M) {
                unsigned short* crow = Cs + (size_t)(off_e + m) * N;
#pragma unroll
                for (int ni = 0; ni < 4; ni++) {
                    float v = acc[mi][ni][rr];
                    if (EPI) v = fmaxf(v + bv[ni], 0.0f);
                    crow[n0 + nW + ni * 16 + lr] = f2bf(v);
                }
            }
        }
    }
}

// ---------------- LN1 over F, in-place ----------------

__global__ __launch_bounds__(256) void k_ln1(unsigned short* __restrict__ H,
        const float* __restrict__ g, const float* __restrict__ b,
        const int* __restrict__ assign_e)
{
    size_t a = blockIdx.x;
    int e = assign_e[a];
    unsigned short* row = H + a * FF;
    int tid = threadIdx.x;
    uint4 u0 = *(const uint4*)(row + tid * 16);
    uint4 u1 = *(const uint4*)(row + tid * 16 + 8);
    float v[16];
    unp(u0.x, v[0], v[1]);  unp(u0.y, v[2], v[3]);
    unp(u0.z, v[4], v[5]);  unp(u0.w, v[6], v[7]);
    unp(u1.x, v[8], v[9]);  unp(u1.y, v[10], v[11]);
    unp(u1.z, v[12], v[13]); unp(u1.w, v[14], v[15]);
    float s = 0.f, q = 0.f;
#pragma unroll
    for (int i = 0; i < 16; i++) { s += v[i]; q += v[i] * v[i]; }
#pragma unroll
    for (int off = 32; off; off >>= 1) { s += __shfl_xor(s, off); q += __shfl_xor(q, off); }
    __shared__ float red[8];
    int wv = tid >> 6, lane = tid & 63;
    if (lane == 0) { red[wv * 2] = s; red[wv * 2 + 1] = q; }
    __syncthreads();
    s = red[0] + red[2] + red[4] + red[6];
    q = red[1] + red[3] + red[5] + red[7];
    float mu = s * (1.0f / FF);
    float var = q * (1.0f / FF) - mu * mu;
    float rstd = rsqrtf(var + LN_EPS);
    const float* gg = g + (size_t)e * FF + tid * 16;
    const float* bb = b + (size_t)e * FF + tid * 16;
    float4 G0 = *(const float4*)(gg);      float4 G1 = *(const float4*)(gg + 4);
    float4 G2 = *(const float4*)(gg + 8);  float4 G3 = *(const float4*)(gg + 12);
    float4 B0 = *(const float4*)(bb);      float4 B1 = *(const float4*)(bb + 4);
    float4 B2 = *(const float4*)(bb + 8);  float4 B3 = *(const float4*)(bb + 12);
    float gvv[16] = {G0.x,G0.y,G0.z,G0.w,G1.x,G1.y,G1.z,G1.w,G2.x,G2.y,G2.z,G2.w,G3.x,G3.y,G3.z,G3.w};
    float bvv[16] = {B0.x,B0.y,B0.z,B0.w,B1.x,B1.y,B1.z,B1.w,B2.x,B2.y,B2.z,B2.w,B3.x,B3.y,B3.z,B3.w};
#pragma unroll
    for (int i = 0; i < 16; i++) v[i] = (v[i] - mu) * rstd * gvv[i] + bvv[i];
    u0.x = pk(v[0], v[1]);  u0.y = pk(v[2], v[3]);
    u0.z = pk(v[4], v[5]);  u0.w = pk(v[6], v[7]);
    u1.x = pk(v[8], v[9]);  u1.y = pk(v[10], v[11]);
    u1.z = pk(v[12], v[13]); u1.w = pk(v[14], v[15]);
    *(uint4*)(row + tid * 16) = u0;
    *(uint4*)(row + tid * 16 + 8) = u1;
}

// ---------------- combine: sum split-K partials + bias + relu + LN2 + gate --

__global__ __launch_bounds__(256) void k_comb(const unsigned short* __restrict__ Yp,
        const float* __restrict__ g, const float* __restrict__ b2,
        const float* __restrict__ be,
        const int* __restrict__ slot, const float* __restrict__ topk_p,
        const int* __restrict__ assign_e, float* __restrict__ out)
{
    int t = blockIdx.x;
    int s0 = slot[2 * t], s1 = slot[2 * t + 1];
    float p0 = topk_p[2 * t], p1 = topk_p[2 * t + 1];
    int e0 = assign_e[s0], e1 = assign_e[s1];
    int tid = threadIdx.x;
    int d = tid * 4;
    const unsigned short* Y1 = Yp + (size_t)NA * DM;
    uint2 ua0 = *(const uint2*)(Yp + (size_t)s0 * DM + d);
    uint2 ua1 = *(const uint2*)(Y1 + (size_t)s0 * DM + d);
    uint2 ub0 = *(const uint2*)(Yp + (size_t)s1 * DM + d);
    uint2 ub1 = *(const uint2*)(Y1 + (size_t)s1 * DM + d);
    float4 bza = *(const float4*)(b2 + (size_t)e0 * DM + d);
    float4 bzb = *(const float4*)(b2 + (size_t)e1 * DM + d);
    float x0, x1, y0, y1;
    float va[4], vb[4];
    unp(ua0.x, x0, x1); unp(ua1.x, y0, y1);
    va[0] = fmaxf(x0 + y0 + bza.x, 0.f); va[1] = fmaxf(x1 + y1 + bza.y, 0.f);
    unp(ua0.y, x0, x1); unp(ua1.y, y0, y1);
    va[2] = fmaxf(x0 + y0 + bza.z, 0.f); va[3] = fmaxf(x1 + y1 + bza.w, 0.f);
    unp(ub0.x, x0, x1); unp(ub1.x, y0, y1);
    vb[0] = fmaxf(x0 + y0 + bzb.x, 0.f); vb[1] = fmaxf(x1 + y1 + bzb.y, 0.f);
    unp(ub0.y, x0, x1); unp(ub1.y, y0, y1);
    vb[2] = fmaxf(x0 + y0 + bzb.z, 0.f); vb[3] = fmaxf(x1 + y1 + bzb.w, 0.f);

    float sa = 0.f, qa = 0.f, sb = 0.f, qb = 0.f;
#pragma unroll
    for (int i = 0; i < 4; i++) {
        sa += va[i]; qa += va[i] * va[i];
        sb += vb[i]; qb += vb[i] * vb[i];
    }
#pragma unroll
    for (int off = 32; off; off >>= 1) {
        sa += __shfl_xor(sa, off); qa += __shfl_xor(qa, off);
        sb += __shfl_xor(sb, off); qb += __shfl_xor(qb, off);
    }
    __shared__ float red[16];
    int wv = tid >> 6, lane = tid & 63;
    if (lane == 0) { red[wv*4+0]=sa; red[wv*4+1]=qa; red[wv*4+2]=sb; red[wv*4+3]=qb; }
    __syncthreads();
    sa = red[0] + red[4] + red[8]  + red[12];
    qa = red[1] + red[5] + red[9]  + red[13];
    sb = red[2] + red[6] + red[10] + red[14];
    qb = red[3] + red[7] + red[11] + red[15];
    float mua = sa * (1.0f / DM), vara = qa * (1.0f / DM) - mua * mua;
    float ra = rsqrtf(vara + LN_EPS);
    float mub = sb * (1.0f / DM), varb = qb * (1.0f / DM) - mub * mub;
    float rb = rsqrtf(varb + LN_EPS);
    float4 ga  = *(const float4*)(g + (size_t)e0 * DM + d);
    float4 ba  = *(const float4*)(be + (size_t)e0 * DM + d);
    float4 gb4 = *(const float4*)(g + (size_t)e1 * DM + d);
    float4 bb4 = *(const float4*)(be + (size_t)e1 * DM + d);
    float4 o;
    o.x = p0 * ((va[0] - mua) * ra * ga.x + ba.x) + p1 * ((vb[0] - mub) * rb * gb4.x + bb4.x);
    o.y = p0 * ((va[1] - mua) * ra * ga.y + ba.y) + p1 * ((vb[1] - mub) * rb * gb4.y + bb4.y);
    o.z = p0 * ((va[2] - mua) * ra * ga.z + ba.z) + p1 * ((vb[2] - mub) * rb * gb4.z + bb4.z);
    o.w = p0 * ((va[3] - mua) * ra * ga.w + ba.w) + p1 * ((vb[3] - mub) * rb * gb4.w + bb4.w);
    *(float4*)(out + (size_t)t * DM + d) = o;
}

// ---------------- launch ----------------

extern "C" void kernel_launch(void* const* d_in, const int* in_sizes, int n_in,
                              void* d_out, int out_size, void* d_ws, size_t ws_size,
                              hipStream_t stream) {
    const float* x   = (const float*)d_in[0];
    const float* Wr  = (const float*)d_in[1];
    const float* br  = (const float*)d_in[2];
    const float* W1  = (const float*)d_in[3];
    const float* b1  = (const float*)d_in[4];
    const float* g1  = (const float*)d_in[5];
    const float* be1 = (const float*)d_in[6];
    const float* W2  = (const float*)d_in[7];
    const float* b2  = (const float*)d_in[8];
    const float* g2  = (const float*)d_in[9];
    const float* be2 = (const float*)d_in[10];
    float* out = (float*)d_out;

    char* w = (char*)d_ws;
    int*   cnt        = (int*)(w);
    int*   offs       = (int*)(w + 128);
    int*   topk_idx   = (int*)(w + 512);
    float* topk_p     = (float*)(w + 512 + (32 << 10));
    int*   assign_tok = (int*)(w + 512 + (64 << 10));
    int*   assign_e   = (int*)(w + 512 + (96 << 10));
    int*   slot       = (int*)(w + 512 + (128 << 10));
    unsigned short* xb  = (unsigned short*)(w + ((size_t)1 << 20));
    unsigned short* W1T = (unsigned short*)(w + ((size_t)9 << 20));    // [E][F][D] bf16
    unsigned short* W2T = (unsigned short*)(w + ((size_t)73 << 20));   // [E][D][F] bf16
    unsigned short* Hb  = (unsigned short*)(w + ((size_t)137 << 20));  // [NA][F] bf16
    unsigned short* Yp  = (unsigned short*)(w + ((size_t)201 << 20));  // [2][NA][D] bf16

    // prep: z 0..7 transpose W1, 8..15 transpose W2, 16 router (+x->bf16)
    k_prep<<<dim3(1024, 1, 17), 256, 0, stream>>>(
        W1, W2, W1T, W2T, x, Wr, br, xb, topk_idx, topk_p);
    k_route2<<<1, 256, 0, stream>>>(topk_idx, cnt, offs, assign_tok, assign_e, slot);
    // GEMM1: gathered x rows x W1T -> Hb(+bias,relu); K=1024, grid 8e*32y*32xn
    k_gemm<true, true><<<8 * 32 * 32, 256, 0, stream>>>(
        xb, W1T, b1, Hb, cnt, offs, assign_tok, DM, FF, DM, DM, 32, 32, 0);
    k_ln1<<<NA, 256, 0, stream>>>(Hb, g1, be1, assign_e);
    // GEMM2: Hb x W2T -> Yp partials; Kslice=2048, 2 slices, grid 8e*32y*8xn*2ks
    k_gemm<false, false><<<8 * 32 * 8 * 2, 256, 0, stream>>>(
        Hb, W2T, nullptr, Yp, cnt, offs, nullptr, FF / 2, DM, FF, FF, 32, 8,
        (size_t)NA * DM);
    k_comb<<<NTOK, 256, 0, stream>>>(Yp, g2, b2, be2, slot, topk_p, assign_e, out);
}

// Round 7
// 333.074 us; speedup vs baseline: 1.6094x; 1.1240x over previous
//
#include <hip/hip_runtime.h>

// Mixture-of-Experts, sparse top-2.
// Round 7: persistent-CTA grouped GEMM (4 blocks/CU, no dead blocks),
// expert->XCD pinning, m97-exact K-loop (single 32KB buffer, XOR swizzle,
// global_load_lds 16B, setprio). Split-K GEMM2. 6 launches.

#define E_N 8
#define TOPK 2
#define DM 1024
#define FF 4096
#define NTOK 4096
#define NA 8192
#define LN_EPS 1e-5f
#define NBX 128   // persistent blocks per XCD (1024 total / 8)

typedef __attribute__((ext_vector_type(4))) float f32x4;
typedef __attribute__((ext_vector_type(8))) short short8;

__device__ __forceinline__ unsigned short f2bf(float f) {
    unsigned int u = __builtin_bit_cast(unsigned int, f);
    u = (u + 0x7FFFu + ((u >> 16) & 1u)) >> 16;   // RNE
    return (unsigned short)u;
}
__device__ __forceinline__ float bf2f(unsigned short h) {
    unsigned int u = ((unsigned int)h) << 16;
    return __builtin_bit_cast(float, u);
}
__device__ __forceinline__ void unp(unsigned int u, float& lo, float& hi) {
    lo = bf2f((unsigned short)(u & 0xffffu));
    hi = bf2f((unsigned short)(u >> 16));
}
__device__ __forceinline__ unsigned int pk(float lo, float hi) {
    return (unsigned int)f2bf(lo) | ((unsigned int)f2bf(hi) << 16);
}

__device__ __forceinline__ void gload16(const unsigned short* g, unsigned short* lds) {
    __builtin_amdgcn_global_load_lds(
        (const __attribute__((address_space(1))) unsigned int*)g,
        (__attribute__((address_space(3))) unsigned int*)lds, 16, 0, 0);
}

// ---------------- prep: W1/W2 transpose (z<16) + router & x->bf16 (z==16) ----

__global__ __launch_bounds__(256) void k_prep(
        const float* __restrict__ W1, const float* __restrict__ W2,
        unsigned short* __restrict__ W1T, unsigned short* __restrict__ W2T,
        const float* __restrict__ x, const float* __restrict__ Wr,
        const float* __restrict__ br, unsigned short* __restrict__ xb,
        int* __restrict__ topk_idx, float* __restrict__ topk_p)
{
    __shared__ float tile[64][65];
    int z = blockIdx.z;
    int tid = threadIdx.x;

    if (z == 16) {
        int wv = tid >> 6, lane = tid & 63;
        int t = blockIdx.x * 4 + wv;
        const float* xr = x + (size_t)t * DM;
        unsigned short* xbr = xb + (size_t)t * DM;
        float a0=0,a1=0,a2=0,a3=0,a4=0,a5=0,a6=0,a7=0;
        for (int d = lane; d < DM; d += 64) {
            float xv = xr[d];
            xbr[d] = f2bf(xv);
            const float4* wp = (const float4*)(Wr + d * 8);
            float4 w0 = wp[0], w1 = wp[1];
            a0 += xv * w0.x; a1 += xv * w0.y; a2 += xv * w0.z; a3 += xv * w0.w;
            a4 += xv * w1.x; a5 += xv * w1.y; a6 += xv * w1.z; a7 += xv * w1.w;
        }
#pragma unroll
        for (int off = 32; off; off >>= 1) {
            a0 += __shfl_xor(a0, off); a1 += __shfl_xor(a1, off);
            a2 += __shfl_xor(a2, off); a3 += __shfl_xor(a3, off);
            a4 += __shfl_xor(a4, off); a5 += __shfl_xor(a5, off);
            a6 += __shfl_xor(a6, off); a7 += __shfl_xor(a7, off);
        }
        if (lane == 0) {
            float l[8] = {a0 + br[0], a1 + br[1], a2 + br[2], a3 + br[3],
                          a4 + br[4], a5 + br[5], a6 + br[6], a7 + br[7]};
            int i0 = 0;
#pragma unroll
            for (int e = 1; e < 8; e++) if (l[e] > l[i0]) i0 = e;
            int i1 = (i0 == 0) ? 1 : 0;
#pragma unroll
            for (int e = 0; e < 8; e++) if (e != i0 && l[e] > l[i1]) i1 = e;
            float p1 = expf(l[i1] - l[i0]);
            float s = 1.0f + p1;
            topk_idx[2 * t]     = i0;
            topk_idx[2 * t + 1] = i1;
            topk_p[2 * t]       = 1.0f / s;
            topk_p[2 * t + 1]   = p1 / s;
        }
        return;
    }

    const float* src; unsigned short* dst; int R, C, bx, by;
    if (z < 8) {
        R = DM; C = FF;
        src = W1 + (size_t)z * R * C;  dst = W1T + (size_t)z * R * C;
        bx = blockIdx.x & 63; by = blockIdx.x >> 6;
    } else {
        R = FF; C = DM;
        src = W2 + (size_t)(z - 8) * R * C;  dst = W2T + (size_t)(z - 8) * R * C;
        bx = blockIdx.x & 15; by = blockIdx.x >> 4;
    }
    const float* s = src + (size_t)(by * 64) * C + bx * 64;
    unsigned short* d = dst + (size_t)(bx * 64) * R + by * 64;
    int lr = tid >> 4, lc = (tid & 15) * 4;
#pragma unroll
    for (int p = 0; p < 4; p++) {
        float4 v = *(const float4*)(s + (size_t)(lr + p * 16) * C + lc);
        tile[lr + p * 16][lc] = v.x;     tile[lr + p * 16][lc + 1] = v.y;
        tile[lr + p * 16][lc + 2] = v.z; tile[lr + p * 16][lc + 3] = v.w;
    }
    __syncthreads();
    int rc = (tid & 7) * 8;
#pragma unroll
    for (int p = 0; p < 2; p++) {
        int cc = (tid >> 3) + p * 32;
        float a0 = tile[rc + 0][cc], a1 = tile[rc + 1][cc];
        float a2 = tile[rc + 2][cc], a3 = tile[rc + 3][cc];
        float a4 = tile[rc + 4][cc], a5 = tile[rc + 5][cc];
        float a6 = tile[rc + 6][cc], a7 = tile[rc + 7][cc];
        uint4 o;
        o.x = pk(a0, a1); o.y = pk(a2, a3); o.z = pk(a4, a5); o.w = pk(a6, a7);
        *(uint4*)(d + (size_t)cc * R + rc) = o;
    }
}

// ---------------- route: histogram + prefix + scatter, one block ------------

__global__ __launch_bounds__(256) void k_route2(const int* __restrict__ topk_idx,
        int* __restrict__ cnt, int* __restrict__ offs,
        int* __restrict__ assign_tok, int* __restrict__ assign_e,
        int* __restrict__ slot)
{
    __shared__ int h[8], base[8];
    int tid = threadIdx.x;
    if (tid < 8) h[tid] = 0;
    __syncthreads();
    int el[32];
#pragma unroll
    for (int i = 0; i < 32; i++) {
        int idx = tid * 32 + i;
        el[i] = topk_idx[idx];
        atomicAdd(&h[el[i]], 1);
    }
    __syncthreads();
    if (tid == 0) {
        int s = 0;
        for (int e = 0; e < E_N; e++) { offs[e] = s; cnt[e] = h[e]; base[e] = s; s += h[e]; }
        offs[E_N] = s;
    }
    __syncthreads();
    if (tid < 8) h[tid] = base[tid];
    __syncthreads();
#pragma unroll
    for (int i = 0; i < 32; i++) {
        int idx = tid * 32 + i;
        int e = el[i];
        int pos = atomicAdd(&h[e], 1);
        assign_tok[pos] = idx >> 1;
        assign_e[pos] = e;
        slot[idx] = pos;
    }
}

// ---------------- persistent grouped GEMM, 128x128, 4 waves, m97 K-loop -----
// Block bid is pinned to expert e = bid&7 (== its XCD under round-robin
// dispatch). lb = bid>>3 in [0,128) strides the expert's live tile list
// t = ((ks*GX)+xn)*nrows + r, so consecutive blocks share a B panel in L2.
// Per tile: zero acc, K-loop {sync; stage(gload16, inv-swizzled src); sync;
// 2x(ds_read swizzled + 16 MFMA, setprio)}; epilogue bias/relu/store.

template<bool GATHER, bool EPI>
__global__ __launch_bounds__(256, 4) void k_gemm(
    const unsigned short* __restrict__ A,
    const unsigned short* __restrict__ BT,
    const float* __restrict__ bias,
    unsigned short* __restrict__ C,
    const int* __restrict__ cnt, const int* __restrict__ offs,
    const int* __restrict__ gather_tok,
    int Kslice, int N, int ldA, int ldB, int GX, int KS, size_t slicePitch)
{
    __shared__ __align__(1024) char lds[32768];   // A 16KB | B 16KB

    int bid = blockIdx.x;
    int e = bid & 7;                 // expert == XCD
    int lb = bid >> 3;
    int M = cnt[e];
    if (M <= 0) return;
    int off_e = offs[e];
    int nrows = (M + 127) >> 7;
    int ntiles = nrows * GX * KS;

    int tid = threadIdx.x;
    int wv = tid >> 6, lane = tid & 63;
    int lr = lane & 15, hi = lane >> 4;
    int mW = (wv >> 1) * 64, nW = (wv & 1) * 64;
    int colsw = ((lane & 7) ^ (lane >> 3)) * 8;
    int l3 = lane >> 3;
    int nt = Kslice >> 6;

    for (int t = lb; t < ntiles; t += NBX) {
        int r = t % nrows;
        int q = t / nrows;
        int xn = q % GX;
        int ks = q / GX;
        int m0 = r * 128;
        int n0 = xn * 128;
        int kbase = ks * Kslice;

        const unsigned short* aptr[4];
        const unsigned short* bptr[4];
#pragma unroll
        for (int i = 0; i < 4; i++) {
            int j = wv * 4 + i;
            int rr = m0 + j * 8 + l3; rr = (rr < M) ? rr : (M - 1);
            size_t arow = GATHER ? (size_t)gather_tok[off_e + rr] : (size_t)(off_e + rr);
            aptr[i] = A + arow * (size_t)ldA + kbase + colsw;
            int rb = n0 + j * 8 + l3;
            bptr[i] = BT + ((size_t)e * N + rb) * (size_t)ldB + kbase + colsw;
        }

        f32x4 acc[4][4];
        f32x4 zz = {0.f, 0.f, 0.f, 0.f};
#pragma unroll
        for (int mi = 0; mi < 4; mi++)
#pragma unroll
            for (int ni = 0; ni < 4; ni++) acc[mi][ni] = zz;

        for (int kt = 0; kt < nt; ++kt) {
            __syncthreads();                  // prev tile fully consumed
#pragma unroll
            for (int i = 0; i < 4; i++) {
                gload16(aptr[i] + kt * 64, (unsigned short*)(lds + (wv * 4 + i) * 1024));
                gload16(bptr[i] + kt * 64, (unsigned short*)(lds + 16384 + (wv * 4 + i) * 1024));
            }
            __syncthreads();                  // drains vmcnt before barrier
#pragma unroll
            for (int kss = 0; kss < 2; kss++) {
                int cb = (kss * 64 + hi * 16) ^ ((lr & 7) << 4);
                short8 afr[4], bfr[4];
#pragma unroll
                for (int ni = 0; ni < 4; ni++)
                    bfr[ni] = *(const short8*)(lds + 16384 + (nW + ni * 16 + lr) * 128 + cb);
#pragma unroll
                for (int mi = 0; mi < 4; mi++)
                    afr[mi] = *(const short8*)(lds + (mW + mi * 16 + lr) * 128 + cb);
                __builtin_amdgcn_s_setprio(1);
#pragma unroll
                for (int mi = 0; mi < 4; mi++)
#pragma unroll
                    for (int ni = 0; ni < 4; ni++)
                        acc[mi][ni] = __builtin_amdgcn_mfma_f32_16x16x32_bf16(
                            afr[mi], bfr[ni], acc[mi][ni], 0, 0, 0);
                __builtin_amdgcn_s_setprio(0);
            }
        }

        unsigned short* Cs = C + ks * slicePitch;
        float bv[4] = {0.f, 0.f, 0.f, 0.f};
        if (EPI) {
#pragma unroll
            for (int ni = 0; ni < 4; ni++)
                bv[ni] = bias[(size_t)e * N + (n0 + nW + ni * 16 + lr)];
        }
#pragma unroll
        for (int mi = 0; mi < 4; mi++) {
            int mb = m0 + mW + mi * 16 + hi * 4;
#pragma unroll
            for (int rr = 0; rr < 4; rr++) {
                int m = mb + rr;
                if (m < M) {
                    unsigned short* crow = Cs + (size_t)(off_e + m) * N;
#pragma unroll
                    for (int ni = 0; ni < 4; ni++) {
                        float v = acc[mi][ni][rr];
                        if (EPI) v = fmaxf(v + bv[ni], 0.0f);
                        crow[n0 + nW + ni * 16 + lr] = f2bf(v);
                    }
                }
            }
        }
    }
}

// ---------------- LN1 over F, in-place ----------------

__global__ __launch_bounds__(256) void k_ln1(unsigned short* __restrict__ H,
        const float* __restrict__ g, const float* __restrict__ b,
        const int* __restrict__ assign_e)
{
    size_t a = blockIdx.x;
    int e = assign_e[a];
    unsigned short* row = H + a * FF;
    int tid = threadIdx.x;
    uint4 u0 = *(const uint4*)(row + tid * 16);
    uint4 u1 = *(const uint4*)(row + tid * 16 + 8);
    float v[16];
    unp(u0.x, v[0], v[1]);  unp(u0.y, v[2], v[3]);
    unp(u0.z, v[4], v[5]);  unp(u0.w, v[6], v[7]);
    unp(u1.x, v[8], v[9]);  unp(u1.y, v[10], v[11]);
    unp(u1.z, v[12], v[13]); unp(u1.w, v[14], v[15]);
    float s = 0.f, q = 0.f;
#pragma unroll
    for (int i = 0; i < 16; i++) { s += v[i]; q += v[i] * v[i]; }
#pragma unroll
    for (int off = 32; off; off >>= 1) { s += __shfl_xor(s, off); q += __shfl_xor(q, off); }
    __shared__ float red[8];
    int wv = tid >> 6, lane = tid & 63;
    if (lane == 0) { red[wv * 2] = s; red[wv * 2 + 1] = q; }
    __syncthreads();
    s = red[0] + red[2] + red[4] + red[6];
    q = red[1] + red[3] + red[5] + red[7];
    float mu = s * (1.0f / FF);
    float var = q * (1.0f / FF) - mu * mu;
    float rstd = rsqrtf(var + LN_EPS);
    const float* gg = g + (size_t)e * FF + tid * 16;
    const float* bb = b + (size_t)e * FF + tid * 16;
    float4 G0 = *(const float4*)(gg);      float4 G1 = *(const float4*)(gg + 4);
    float4 G2 = *(const float4*)(gg + 8);  float4 G3 = *(const float4*)(gg + 12);
    float4 B0 = *(const float4*)(bb);      float4 B1 = *(const float4*)(bb + 4);
    float4 B2 = *(const float4*)(bb + 8);  float4 B3 = *(const float4*)(bb + 12);
    float gvv[16] = {G0.x,G0.y,G0.z,G0.w,G1.x,G1.y,G1.z,G1.w,G2.x,G2.y,G2.z,G2.w,G3.x,G3.y,G3.z,G3.w};
    float bvv[16] = {B0.x,B0.y,B0.z,B0.w,B1.x,B1.y,B1.z,B1.w,B2.x,B2.y,B2.z,B2.w,B3.x,B3.y,B3.z,B3.w};
#pragma unroll
    for (int i = 0; i < 16; i++) v[i] = (v[i] - mu) * rstd * gvv[i] + bvv[i];
    u0.x = pk(v[0], v[1]);  u0.y = pk(v[2], v[3]);
    u0.z = pk(v[4], v[5]);  u0.w = pk(v[6], v[7]);
    u1.x = pk(v[8], v[9]);  u1.y = pk(v[10], v[11]);
    u1.z = pk(v[12], v[13]); u1.w = pk(v[14], v[15]);
    *(uint4*)(row + tid * 16) = u0;
    *(uint4*)(row + tid * 16 + 8) = u1;
}

// ---------------- combine: sum split-K partials + bias + relu + LN2 + gate --

__global__ __launch_bounds__(256) void k_comb(const unsigned short* __restrict__ Yp,
        const float* __restrict__ g, const float* __restrict__ b2,
        const float* __restrict__ be,
        const int* __restrict__ slot, const float* __restrict__ topk_p,
        const int* __restrict__ assign_e, float* __restrict__ out)
{
    int t = blockIdx.x;
    int s0 = slot[2 * t], s1 = slot[2 * t + 1];
    float p0 = topk_p[2 * t], p1 = topk_p[2 * t + 1];
    int e0 = assign_e[s0], e1 = assign_e[s1];
    int tid = threadIdx.x;
    int d = tid * 4;
    const unsigned short* Y1 = Yp + (size_t)NA * DM;
    uint2 ua0 = *(const uint2*)(Yp + (size_t)s0 * DM + d);
    uint2 ua1 = *(const uint2*)(Y1 + (size_t)s0 * DM + d);
    uint2 ub0 = *(const uint2*)(Yp + (size_t)s1 * DM + d);
    uint2 ub1 = *(const uint2*)(Y1 + (size_t)s1 * DM + d);
    float4 bza = *(const float4*)(b2 + (size_t)e0 * DM + d);
    float4 bzb = *(const float4*)(b2 + (size_t)e1 * DM + d);
    float x0, x1, y0, y1;
    float va[4], vb[4];
    unp(ua0.x, x0, x1); unp(ua1.x, y0, y1);
    va[0] = fmaxf(x0 + y0 + bza.x, 0.f); va[1] = fmaxf(x1 + y1 + bza.y, 0.f);
    unp(ua0.y, x0, x1); unp(ua1.y, y0, y1);
    va[2] = fmaxf(x0 + y0 + bza.z, 0.f); va[3] = fmaxf(x1 + y1 + bza.w, 0.f);
    unp(ub0.x, x0, x1); unp(ub1.x, y0, y1);
    vb[0] = fmaxf(x0 + y0 + bzb.x, 0.f); vb[1] = fmaxf(x1 + y1 + bzb.y, 0.f);
    unp(ub0.y, x0, x1); unp(ub1.y, y0, y1);
    vb[2] = fmaxf(x0 + y0 + bzb.z, 0.f); vb[3] = fmaxf(x1 + y1 + bzb.w, 0.f);

    float sa = 0.f, qa = 0.f, sb = 0.f, qb = 0.f;
#pragma unroll
    for (int i = 0; i < 4; i++) {
        sa += va[i]; qa += va[i] * va[i];
        sb += vb[i]; qb += vb[i] * vb[i];
    }
#pragma unroll
    for (int off = 32; off; off >>= 1) {
        sa += __shfl_xor(sa, off); qa += __shfl_xor(qa, off);
        sb += __shfl_xor(sb, off); qb += __shfl_xor(qb, off);
    }
    __shared__ float red[16];
    int wv = tid >> 6, lane = tid & 63;
    if (lane == 0) { red[wv*4+0]=sa; red[wv*4+1]=qa; red[wv*4+2]=sb; red[wv*4+3]=qb; }
    __syncthreads();
    sa = red[0] + red[4] + red[8]  + red[12];
    qa = red[1] + red[5] + red[9]  + red[13];
    sb = red[2] + red[6] + red[10] + red[14];
    qb = red[3] + red[7] + red[11] + red[15];
    float mua = sa * (1.0f / DM), vara = qa * (1.0f / DM) - mua * mua;
    float ra = rsqrtf(vara + LN_EPS);
    float mub = sb * (1.0f / DM), varb = qb * (1.0f / DM) - mub * mub;
    float rb = rsqrtf(varb + LN_EPS);
    float4 ga  = *(const float4*)(g + (size_t)e0 * DM + d);
    float4 ba  = *(const float4*)(be + (size_t)e0 * DM + d);
    float4 gb4 = *(const float4*)(g + (size_t)e1 * DM + d);
    float4 bb4 = *(const float4*)(be + (size_t)e1 * DM + d);
    float4 o;
    o.x = p0 * ((va[0] - mua) * ra * ga.x + ba.x) + p1 * ((vb[0] - mub) * rb * gb4.x + bb4.x);
    o.y = p0 * ((va[1] - mua) * ra * ga.y + ba.y) + p1 * ((vb[1] - mub) * rb * gb4.y + bb4.y);
    o.z = p0 * ((va[2] - mua) * ra * ga.z + ba.z) + p1 * ((vb[2] - mub) * rb * gb4.z + bb4.z);
    o.w = p0 * ((va[3] - mua) * ra * ga.w + ba.w) + p1 * ((vb[3] - mub) * rb * gb4.w + bb4.w);
    *(float4*)(out + (size_t)t * DM + d) = o;
}

// ---------------- launch ----------------

extern "C" void kernel_launch(void* const* d_in, const int* in_sizes, int n_in,
                              void* d_out, int out_size, void* d_ws, size_t ws_size,
                              hipStream_t stream) {
    const float* x   = (const float*)d_in[0];
    const float* Wr  = (const float*)d_in[1];
    const float* br  = (const float*)d_in[2];
    const float* W1  = (const float*)d_in[3];
    const float* b1  = (const float*)d_in[4];
    const float* g1  = (const float*)d_in[5];
    const float* be1 = (const float*)d_in[6];
    const float* W2  = (const float*)d_in[7];
    const float* b2  = (const float*)d_in[8];
    const float* g2  = (const float*)d_in[9];
    const float* be2 = (const float*)d_in[10];
    float* out = (float*)d_out;

    char* w = (char*)d_ws;
    int*   cnt        = (int*)(w);
    int*   offs       = (int*)(w + 128);
    int*   topk_idx   = (int*)(w + 512);
    float* topk_p     = (float*)(w + 512 + (32 << 10));
    int*   assign_tok = (int*)(w + 512 + (64 << 10));
    int*   assign_e   = (int*)(w + 512 + (96 << 10));
    int*   slot       = (int*)(w + 512 + (128 << 10));
    unsigned short* xb  = (unsigned short*)(w + ((size_t)1 << 20));
    unsigned short* W1T = (unsigned short*)(w + ((size_t)9 << 20));    // [E][F][D] bf16
    unsigned short* W2T = (unsigned short*)(w + ((size_t)73 << 20));   // [E][D][F] bf16
    unsigned short* Hb  = (unsigned short*)(w + ((size_t)137 << 20));  // [NA][F] bf16
    unsigned short* Yp  = (unsigned short*)(w + ((size_t)201 << 20));  // [2][NA][D] bf16

    // prep: z 0..7 transpose W1, 8..15 transpose W2, 16 router (+x->bf16)
    k_prep<<<dim3(1024, 1, 17), 256, 0, stream>>>(
        W1, W2, W1T, W2T, x, Wr, br, xb, topk_idx, topk_p);
    k_route2<<<1, 256, 0, stream>>>(topk_idx, cnt, offs, assign_tok, assign_e, slot);
    // GEMM1: gathered x rows x W1T -> Hb(+bias,relu); K=1024, GX=32, KS=1
    k_gemm<true, true><<<8 * NBX, 256, 0, stream>>>(
        xb, W1T, b1, Hb, cnt, offs, assign_tok, DM, FF, DM, DM, 32, 1, 0);
    k_ln1<<<NA, 256, 0, stream>>>(Hb, g1, be1, assign_e);
    // GEMM2: Hb x W2T -> Yp partials; Kslice=2048, KS=2, GX=8
    k_gemm<false, false><<<8 * NBX, 256, 0, stream>>>(
        Hb, W2T, nullptr, Yp, cnt, offs, nullptr, FF / 2, DM, FF, FF, 8, 2,
        (size_t)NA * DM);
    k_comb<<<NTOK, 256, 0, stream>>>(Yp, g2, b2, be2, slot, topk_p, assign_e, out);
}